// Round 10
// baseline (394.596 us; speedup 1.0000x reference)
//
#include <hip/hip_runtime.h>
#include <hip/hip_bf16.h>

// PointInstanceNorm — DIAGNOSTIC ROUND (intentional regression, R9 + probe).
// Structure is R9's proven 161.1 us config; K1 additionally re-sweeps its
// chunk 7 extra times with keep-alive discarded loads. Purpose:
//   * pin_stats becomes slower than the harness's 152 us fills -> appears in
//     the top-5 rocprof rows WITH dur_us and FETCH_SIZE.
//   * per-sweep time t = (total - 161)/7  -> Infinity-Cache read BW.
//   * K1_base = dur(pin_stats) - 7t       -> the K1/K3 cost split.
//   * FETCH_SIZE of the row: small => L3 retains x across replays (reuse
//     model confirmed); ~1.8 GB => L3 not retaining, model wrong.
// Math is bit-identical to R9 (only pass 0 accumulates): absmax 0.03125.

#define EPS 1e-5f

typedef float f32x4 __attribute__((ext_vector_type(4)));  // nt builtins reject HIP_vector_type

// ---------------------------------------------------------------- kernel 1
__global__ __launch_bounds__(256) void pin_stats(
    const float4* __restrict__ x4, float* __restrict__ partials,
    int ppb, long N) {
    const int tid   = threadIdx.x;
    const int lane  = tid & 63;
    const int wave  = tid >> 6;
    const int cgrp  = lane & 15;
    const int quart = lane >> 4;
    const long bchunk = (long)gridDim.x - 1 - blockIdx.x;   // descending sweep
    const long block_start = bchunk * ppb;

    float4 s = make_float4(0.f, 0.f, 0.f, 0.f);
    float4 q = make_float4(0.f, 0.f, 0.f, 0.f);

    const int iters = ppb >> 4;
    const long lane_base = (block_start + wave * 4 + quart) * 16 + cgrp;

    if (block_start + ppb <= N) {
        // pass 0: real accumulation (identical to R9)
        #pragma unroll 8
        for (int it = 0; it < iters; ++it) {
            float4 v = x4[lane_base + (long)it * 256];
            s.x += v.x; s.y += v.y; s.z += v.z; s.w += v.w;
            q.x += v.x * v.x; q.y += v.y * v.y; q.z += v.z * v.z; q.w += v.w * v.w;
        }
        // passes 1..7: DIAGNOSTIC re-sweeps. "memory" clobber defeats CSE
        // (loads must re-issue); keep-alive asm defeats DCE (rule #17).
        #pragma unroll 1
        for (int pass = 1; pass < 8; ++pass) {
            asm volatile("" ::: "memory");
            #pragma unroll 8
            for (int it = 0; it < iters; ++it) {
                float4 v = x4[lane_base + (long)it * 256];
                asm volatile("" :: "v"(v.x), "v"(v.y), "v"(v.z), "v"(v.w));
            }
        }
    } else {
        for (int it = 0; it < iters; ++it) {
            long p = block_start + (long)it * 16 + wave * 4 + quart;
            if (p < N) {
                float4 v = x4[p * 16 + cgrp];
                s.x += v.x; s.y += v.y; s.z += v.z; s.w += v.w;
                q.x += v.x * v.x; q.y += v.y * v.y; q.z += v.z * v.z; q.w += v.w * v.w;
            }
        }
    }

    #pragma unroll
    for (int off = 16; off <= 32; off <<= 1) {
        s.x += __shfl_xor(s.x, off); s.y += __shfl_xor(s.y, off);
        s.z += __shfl_xor(s.z, off); s.w += __shfl_xor(s.w, off);
        q.x += __shfl_xor(q.x, off); q.y += __shfl_xor(q.y, off);
        q.z += __shfl_xor(q.z, off); q.w += __shfl_xor(q.w, off);
    }

    __shared__ float lds[4][16][8];
    if (lane < 16) {
        lds[wave][lane][0] = s.x; lds[wave][lane][1] = s.y;
        lds[wave][lane][2] = s.z; lds[wave][lane][3] = s.w;
        lds[wave][lane][4] = q.x; lds[wave][lane][5] = q.y;
        lds[wave][lane][6] = q.z; lds[wave][lane][7] = q.w;
    }
    __syncthreads();

    if (tid < 128) {
        int stat = tid >> 6;
        int ch   = tid & 63;
        int cg   = ch >> 2;
        int j    = ch & 3;
        float v = lds[0][cg][stat * 4 + j] + lds[1][cg][stat * 4 + j]
                + lds[2][cg][stat * 4 + j] + lds[3][cg][stat * 4 + j];
        partials[bchunk * 128 + tid] = v;
    }
}

// ---------------------------------------------------------------- kernel 2
__global__ __launch_bounds__(64) void pin_scale(
    const float* __restrict__ partials,
    const float* __restrict__ weight, const float* __restrict__ bias,
    const int* __restrict__ offs,
    float* __restrict__ scale, float* __restrict__ shift, int ppb) {
    const int s = blockIdx.x;
    const int c = threadIdx.x;
    const int b0 = offs[s] / ppb;
    const int b1 = offs[s + 1] / ppb;

    float sum = 0.f, sq = 0.f;
    for (int blk = b0; blk < b1; ++blk) {
        sum += partials[(long)blk * 128 + c];
        sq  += partials[(long)blk * 128 + 64 + c];
    }
    float cnt  = (float)(offs[s + 1] - offs[s]);
    float mean = sum / cnt;
    float var  = sq / cnt - mean * mean;
    float sc   = weight[c] * rsqrtf(var + EPS);
    scale[s * 64 + c] = sc;
    shift[s * 64 + c] = bias[c] - mean * sc;
}

// ---------------------------------------------------------------- kernel 3
// Identical to R7/R9: plain x loads (L3-served), nt y stores.
#define K3_THREADS 256
#define K3_ITERS 16
__global__ __launch_bounds__(K3_THREADS) void pin_norm(
    const f32x4* __restrict__ x4, const int* __restrict__ bidx,
    const float4* __restrict__ scale4, const float4* __restrict__ shift4,
    f32x4* __restrict__ y4, long total4) {
    const long chunk = (long)blockIdx.x * (K3_THREADS * K3_ITERS);
    const int  tid   = threadIdx.x;
    const long p0    = chunk >> 4;
    const int  seg   = bidx[p0];
    const int  cgrp  = tid & 15;

    const float4 sc = scale4[seg * 16 + cgrp];
    const float4 sh = shift4[seg * 16 + cgrp];

    if (chunk + K3_THREADS * K3_ITERS <= total4) {
        #pragma unroll
        for (int k = 0; k < K3_ITERS; ++k) {
            long i = chunk + (long)k * K3_THREADS + tid;
            f32x4 v = x4[i];
            f32x4 o;
            o.x = v.x * sc.x + sh.x;
            o.y = v.y * sc.y + sh.y;
            o.z = v.z * sc.z + sh.z;
            o.w = v.w * sc.w + sh.w;
            __builtin_nontemporal_store(o, &y4[i]);
        }
    } else {
        for (int k = 0; k < K3_ITERS; ++k) {
            long i = chunk + (long)k * K3_THREADS + tid;
            if (i < total4) {
                f32x4 v = x4[i];
                f32x4 o;
                o.x = v.x * sc.x + sh.x;
                o.y = v.y * sc.y + sh.y;
                o.z = v.z * sc.z + sh.z;
                o.w = v.w * sc.w + sh.w;
                __builtin_nontemporal_store(o, &y4[i]);
            }
        }
    }
}

// ---------------------------------------------------------------- launcher
extern "C" void kernel_launch(void* const* d_in, const int* in_sizes, int n_in,
                              void* d_out, int out_size, void* d_ws, size_t ws_size,
                              hipStream_t stream) {
    const float* x       = (const float*)d_in[0];
    const float* weight  = (const float*)d_in[1];
    const float* bias    = (const float*)d_in[2];
    const int*   offs    = (const int*)d_in[3];
    const int*   bidx    = (const int*)d_in[4];
    float* out = (float*)d_out;

    const long C = in_sizes[1];          // 64
    const long N = (long)in_sizes[0] / C;
    const int  S = in_sizes[3] - 1;      // number of segments

    int ppb = 1024;
    long nb1;
    for (;;) {
        nb1 = (N + ppb - 1) / ppb;
        size_t need = (size_t)(nb1 * 128 + 2 * S * 64) * sizeof(float);
        if (need <= ws_size || ppb >= (1 << 20)) break;
        ppb <<= 1;
    }

    float* partials = (float*)d_ws;
    float* scale    = partials + nb1 * 128;
    float* shift    = scale + S * 64;

    pin_stats<<<(int)nb1, 256, 0, stream>>>((const float4*)x, partials, ppb, N);
    pin_scale<<<S, 64, 0, stream>>>(partials, weight, bias, offs, scale, shift, ppb);

    const long total4 = N * (C / 4);
    const long nb3 = (total4 + (K3_THREADS * K3_ITERS) - 1) / (K3_THREADS * K3_ITERS);
    pin_norm<<<(int)nb3, K3_THREADS, 0, stream>>>(
        (const f32x4*)x, bidx, (const float4*)scale, (const float4*)shift,
        (f32x4*)out, total4);
}

// Round 11
// 255.764 us; speedup vs baseline: 1.5428x; 1.5428x over previous
//
#include <hip/hip_runtime.h>
#include <hip/hip_bf16.h>

// PointInstanceNorm: per-(segment, channel) normalization over [1, N, C] fp32,
// S contiguous equal segments. Structure proven in R7/R9 (161 us):
//   K1: partial sum/sumsq, DESCENDING chunk sweep (leaves x in L3 for K3).
//   K2: fold partials -> fused scale/shift per (seg, channel).
//   K3: y = x*scale + shift, ascending; PLAIN x loads (L3-served),
//       NON-TEMPORAL y stores (write stream must not evict x).
// R10 probe ledger: K1 ~100 us (268 MB cold-HBM @ 2.7 TB/s) vs cache-resident
// re-sweep @ 8 TB/s -> K1 is source-path-limited, not pattern-limited.
// K3 ~55 us (near copy ceiling). This round, ONE variable: ppb 1024 -> 256,
// giving K1 exactly K3's proven grid shape (4096 blocks x 16 iters x 64 KB,
// ~full occupancy vs 46%).

#define EPS 1e-5f

typedef float f32x4 __attribute__((ext_vector_type(4)));  // nt builtins reject HIP_vector_type

// ---------------------------------------------------------------- kernel 1
// 256 threads (4 waves), PPB contiguous points per chunk. Lane l reads the
// float4 of channels 4*(l&15)..+3 of point base+(l>>4): 64 lanes = 4 points
// x 64 channels = 1 KiB contiguous per wave-iteration. Chunk index reversed
// (descending sweep); partials stay chunk-indexed so K2 is unchanged.
__global__ __launch_bounds__(256) void pin_stats(
    const float4* __restrict__ x4, float* __restrict__ partials,
    int ppb, long N) {
    const int tid   = threadIdx.x;
    const int lane  = tid & 63;
    const int wave  = tid >> 6;
    const int cgrp  = lane & 15;
    const int quart = lane >> 4;
    const long bchunk = (long)gridDim.x - 1 - blockIdx.x;   // descending sweep
    const long block_start = bchunk * ppb;

    float4 s = make_float4(0.f, 0.f, 0.f, 0.f);
    float4 q = make_float4(0.f, 0.f, 0.f, 0.f);

    const int iters = ppb >> 4;
    const long lane_base = (block_start + wave * 4 + quart) * 16 + cgrp;

    if (block_start + ppb <= N) {
        #pragma unroll 8
        for (int it = 0; it < iters; ++it) {
            float4 v = x4[lane_base + (long)it * 256];
            s.x += v.x; s.y += v.y; s.z += v.z; s.w += v.w;
            q.x += v.x * v.x; q.y += v.y * v.y; q.z += v.z * v.z; q.w += v.w * v.w;
        }
    } else {
        for (int it = 0; it < iters; ++it) {
            long p = block_start + (long)it * 16 + wave * 4 + quart;
            if (p < N) {
                float4 v = x4[p * 16 + cgrp];
                s.x += v.x; s.y += v.y; s.z += v.z; s.w += v.w;
                q.x += v.x * v.x; q.y += v.y * v.y; q.z += v.z * v.z; q.w += v.w * v.w;
            }
        }
    }

    #pragma unroll
    for (int off = 16; off <= 32; off <<= 1) {
        s.x += __shfl_xor(s.x, off); s.y += __shfl_xor(s.y, off);
        s.z += __shfl_xor(s.z, off); s.w += __shfl_xor(s.w, off);
        q.x += __shfl_xor(q.x, off); q.y += __shfl_xor(q.y, off);
        q.z += __shfl_xor(q.z, off); q.w += __shfl_xor(q.w, off);
    }

    __shared__ float lds[4][16][8];
    if (lane < 16) {
        lds[wave][lane][0] = s.x; lds[wave][lane][1] = s.y;
        lds[wave][lane][2] = s.z; lds[wave][lane][3] = s.w;
        lds[wave][lane][4] = q.x; lds[wave][lane][5] = q.y;
        lds[wave][lane][6] = q.z; lds[wave][lane][7] = q.w;
    }
    __syncthreads();

    if (tid < 128) {
        int stat = tid >> 6;
        int ch   = tid & 63;
        int cg   = ch >> 2;
        int j    = ch & 3;
        float v = lds[0][cg][stat * 4 + j] + lds[1][cg][stat * 4 + j]
                + lds[2][cg][stat * 4 + j] + lds[3][cg][stat * 4 + j];
        partials[bchunk * 128 + tid] = v;
    }
}

// ---------------------------------------------------------------- kernel 2
__global__ __launch_bounds__(64) void pin_scale(
    const float* __restrict__ partials,
    const float* __restrict__ weight, const float* __restrict__ bias,
    const int* __restrict__ offs,
    float* __restrict__ scale, float* __restrict__ shift, int ppb) {
    const int s = blockIdx.x;
    const int c = threadIdx.x;
    const int b0 = offs[s] / ppb;
    const int b1 = offs[s + 1] / ppb;

    float sum = 0.f, sq = 0.f;
    for (int blk = b0; blk < b1; ++blk) {
        sum += partials[(long)blk * 128 + c];
        sq  += partials[(long)blk * 128 + 64 + c];
    }
    float cnt  = (float)(offs[s + 1] - offs[s]);
    float mean = sum / cnt;
    float var  = sq / cnt - mean * mean;
    float sc   = weight[c] * rsqrtf(var + EPS);
    scale[s * 64 + c] = sc;
    shift[s * 64 + c] = bias[c] - mean * sc;
}

// ---------------------------------------------------------------- kernel 3
// y = x*scale + shift, float4 in / nt-float4 out, ascending streaming.
// Identical to R7/R9 (proven): 4096 blocks x 256 threads x 16 float4.
#define K3_THREADS 256
#define K3_ITERS 16
__global__ __launch_bounds__(K3_THREADS) void pin_norm(
    const f32x4* __restrict__ x4, const int* __restrict__ bidx,
    const float4* __restrict__ scale4, const float4* __restrict__ shift4,
    f32x4* __restrict__ y4, long total4) {
    const long chunk = (long)blockIdx.x * (K3_THREADS * K3_ITERS);
    const int  tid   = threadIdx.x;
    const long p0    = chunk >> 4;
    const int  seg   = bidx[p0];
    const int  cgrp  = tid & 15;

    const float4 sc = scale4[seg * 16 + cgrp];
    const float4 sh = shift4[seg * 16 + cgrp];

    if (chunk + K3_THREADS * K3_ITERS <= total4) {
        #pragma unroll
        for (int k = 0; k < K3_ITERS; ++k) {
            long i = chunk + (long)k * K3_THREADS + tid;
            f32x4 v = x4[i];
            f32x4 o;
            o.x = v.x * sc.x + sh.x;
            o.y = v.y * sc.y + sh.y;
            o.z = v.z * sc.z + sh.z;
            o.w = v.w * sc.w + sh.w;
            __builtin_nontemporal_store(o, &y4[i]);
        }
    } else {
        for (int k = 0; k < K3_ITERS; ++k) {
            long i = chunk + (long)k * K3_THREADS + tid;
            if (i < total4) {
                f32x4 v = x4[i];
                f32x4 o;
                o.x = v.x * sc.x + sh.x;
                o.y = v.y * sc.y + sh.y;
                o.z = v.z * sc.z + sh.z;
                o.w = v.w * sc.w + sh.w;
                __builtin_nontemporal_store(o, &y4[i]);
            }
        }
    }
}

// ---------------------------------------------------------------- launcher
extern "C" void kernel_launch(void* const* d_in, const int* in_sizes, int n_in,
                              void* d_out, int out_size, void* d_ws, size_t ws_size,
                              hipStream_t stream) {
    const float* x       = (const float*)d_in[0];
    const float* weight  = (const float*)d_in[1];
    const float* bias    = (const float*)d_in[2];
    const int*   offs    = (const int*)d_in[3];
    const int*   bidx    = (const int*)d_in[4];
    float* out = (float*)d_out;

    const long C = in_sizes[1];          // 64
    const long N = (long)in_sizes[0] / C;
    const int  S = in_sizes[3] - 1;      // number of segments

    // ppb=256 -> 4096 chunks @ N=1M (K3's proven grid shape); partials 2 MB.
    int ppb = 256;
    long nb1;
    for (;;) {
        nb1 = (N + ppb - 1) / ppb;
        size_t need = (size_t)(nb1 * 128 + 2 * S * 64) * sizeof(float);
        if (need <= ws_size || ppb >= (1 << 20)) break;
        ppb <<= 1;
    }

    float* partials = (float*)d_ws;
    float* scale    = partials + nb1 * 128;
    float* shift    = scale + S * 64;

    pin_stats<<<(int)nb1, 256, 0, stream>>>((const float4*)x, partials, ppb, N);
    pin_scale<<<S, 64, 0, stream>>>(partials, weight, bias, offs, scale, shift, ppb);

    const long total4 = N * (C / 4);
    const long nb3 = (total4 + (K3_THREADS * K3_ITERS) - 1) / (K3_THREADS * K3_ITERS);
    pin_norm<<<(int)nb3, K3_THREADS, 0, stream>>>(
        (const f32x4*)x, bidx, (const float4*)scale, (const float4*)shift,
        (f32x4*)out, total4);
}

// Round 12
// 136.983 us; speedup vs baseline: 2.8806x; 1.8671x over previous
//
#include <hip/hip_runtime.h>
#include <hip/hip_bf16.h>

// PointInstanceNorm: per-(segment, channel) normalization over [1, N, C] fp32,
// S contiguous equal segments. Structure proven in R7/R9 (161 us):
//   K1: partial sum/sumsq, DESCENDING chunk sweep (leaves x in L3 for K3),
//       ppb=1024. NEW: dual-stream reads (two 1KB streams 128KB apart) to
//       raise DRAM page/bank parallelism -- every cold-HBM READ observation
//       so far caps at 2.7-3.2 TB/s while writes do 6.9.
//   K2: fold partials -> scale/shift. NEW: parallel fold (8 blocks x 256
//       threads, 4 threads/channel + deterministic LDS tree) -- the old
//       64-thread serial fold was a hidden latency-bound phase.
//   K3: y = x*scale + shift, ascending; PLAIN x loads (L3-served), NT stores
//       (write stream must not evict x). FROZEN (R9).
// Ledger: K1~100us (2.7 TB/s cold read), K3~55us, total 161.
// R11 lesson: ppb=256 exploded K2's serial fold (and stream count); ppb=1024.

#define EPS 1e-5f

typedef float f32x4 __attribute__((ext_vector_type(4)));  // nt builtins reject HIP_vector_type

// ---------------------------------------------------------------- kernel 1
// 256 threads (4 waves), PPB=1024 contiguous points per chunk. Lane l reads
// the float4 of channels 4*(l&15)..+3 of point base+(l>>4): a wave covers
// 1KB contiguous per load. Fast path walks TWO streams: it and it+iters/2
// (128KB apart), independent accumulators -> 2x distinct DRAM pages in
// flight. Chunk index reversed (descending sweep).
__global__ __launch_bounds__(256) void pin_stats(
    const float4* __restrict__ x4, float* __restrict__ partials,
    int ppb, long N) {
    const int tid   = threadIdx.x;
    const int lane  = tid & 63;
    const int wave  = tid >> 6;
    const int cgrp  = lane & 15;
    const int quart = lane >> 4;
    const long bchunk = (long)gridDim.x - 1 - blockIdx.x;   // descending sweep
    const long block_start = bchunk * ppb;

    float4 s = make_float4(0.f, 0.f, 0.f, 0.f);
    float4 q = make_float4(0.f, 0.f, 0.f, 0.f);

    const int iters = ppb >> 4;
    const long lane_base = (block_start + wave * 4 + quart) * 16 + cgrp;

    if (block_start + ppb <= N) {
        const int half = iters >> 1;                  // 32 at ppb=1024
        float4 s1 = make_float4(0.f, 0.f, 0.f, 0.f);
        float4 q1 = make_float4(0.f, 0.f, 0.f, 0.f);
        #pragma unroll 4
        for (int it = 0; it < half; ++it) {
            float4 a = x4[lane_base + (long)it * 256];
            float4 b = x4[lane_base + (long)(it + half) * 256];
            s.x  += a.x; s.y  += a.y; s.z  += a.z; s.w  += a.w;
            q.x  += a.x * a.x; q.y  += a.y * a.y; q.z  += a.z * a.z; q.w  += a.w * a.w;
            s1.x += b.x; s1.y += b.y; s1.z += b.z; s1.w += b.w;
            q1.x += b.x * b.x; q1.y += b.y * b.y; q1.z += b.z * b.z; q1.w += b.w * b.w;
        }
        s.x += s1.x; s.y += s1.y; s.z += s1.z; s.w += s1.w;
        q.x += q1.x; q.y += q1.y; q.z += q1.z; q.w += q1.w;
    } else {
        for (int it = 0; it < iters; ++it) {
            long p = block_start + (long)it * 16 + wave * 4 + quart;
            if (p < N) {
                float4 v = x4[p * 16 + cgrp];
                s.x += v.x; s.y += v.y; s.z += v.z; s.w += v.w;
                q.x += v.x * v.x; q.y += v.y * v.y; q.z += v.z * v.z; q.w += v.w * v.w;
            }
        }
    }

    #pragma unroll
    for (int off = 16; off <= 32; off <<= 1) {
        s.x += __shfl_xor(s.x, off); s.y += __shfl_xor(s.y, off);
        s.z += __shfl_xor(s.z, off); s.w += __shfl_xor(s.w, off);
        q.x += __shfl_xor(q.x, off); q.y += __shfl_xor(q.y, off);
        q.z += __shfl_xor(q.z, off); q.w += __shfl_xor(q.w, off);
    }

    __shared__ float lds[4][16][8];
    if (lane < 16) {
        lds[wave][lane][0] = s.x; lds[wave][lane][1] = s.y;
        lds[wave][lane][2] = s.z; lds[wave][lane][3] = s.w;
        lds[wave][lane][4] = q.x; lds[wave][lane][5] = q.y;
        lds[wave][lane][6] = q.z; lds[wave][lane][7] = q.w;
    }
    __syncthreads();

    if (tid < 128) {
        int stat = tid >> 6;
        int ch   = tid & 63;
        int cg   = ch >> 2;
        int j    = ch & 3;
        float v = lds[0][cg][stat * 4 + j] + lds[1][cg][stat * 4 + j]
                + lds[2][cg][stat * 4 + j] + lds[3][cg][stat * 4 + j];
        partials[bchunk * 128 + tid] = v;
    }
}

// ---------------------------------------------------------------- kernel 2
// One block per segment, 256 threads: 4 threads per channel fold interleaved
// chunk subsets (blk = b0+r, step 4), then a fixed-order LDS tree combines
// the 4 sub-partials. Deterministic; ~4x the load parallelism of the old
// 64-thread serial fold plus 4x fewer iterations per thread.
__global__ __launch_bounds__(256) void pin_scale(
    const float* __restrict__ partials,
    const float* __restrict__ weight, const float* __restrict__ bias,
    const int* __restrict__ offs,
    float* __restrict__ scale, float* __restrict__ shift, int ppb) {
    const int s = blockIdx.x;
    const int c = threadIdx.x & 63;
    const int r = threadIdx.x >> 6;          // 0..3
    const int b0 = offs[s] / ppb;
    const int b1 = offs[s + 1] / ppb;

    float sum = 0.f, sq = 0.f;
    for (int blk = b0 + r; blk < b1; blk += 4) {
        sum += partials[(long)blk * 128 + c];
        sq  += partials[(long)blk * 128 + 64 + c];
    }

    __shared__ float lsum[4][64];
    __shared__ float lsq[4][64];
    lsum[r][c] = sum;
    lsq[r][c]  = sq;
    __syncthreads();

    if (r == 0) {
        float tsum = ((lsum[0][c] + lsum[1][c]) + lsum[2][c]) + lsum[3][c];
        float tsq  = ((lsq[0][c]  + lsq[1][c])  + lsq[2][c])  + lsq[3][c];
        float cnt  = (float)(offs[s + 1] - offs[s]);
        float mean = tsum / cnt;
        float var  = tsq / cnt - mean * mean;
        float sc   = weight[c] * rsqrtf(var + EPS);
        scale[s * 64 + c] = sc;
        shift[s * 64 + c] = bias[c] - mean * sc;
    }
}

// ---------------------------------------------------------------- kernel 3
// y = x*scale + shift, float4 in / nt-float4 out, ascending streaming.
// Identical to R7/R9 (proven): 4096 blocks x 256 threads x 16 float4.
#define K3_THREADS 256
#define K3_ITERS 16
__global__ __launch_bounds__(K3_THREADS) void pin_norm(
    const f32x4* __restrict__ x4, const int* __restrict__ bidx,
    const float4* __restrict__ scale4, const float4* __restrict__ shift4,
    f32x4* __restrict__ y4, long total4) {
    const long chunk = (long)blockIdx.x * (K3_THREADS * K3_ITERS);
    const int  tid   = threadIdx.x;
    const long p0    = chunk >> 4;
    const int  seg   = bidx[p0];
    const int  cgrp  = tid & 15;

    const float4 sc = scale4[seg * 16 + cgrp];
    const float4 sh = shift4[seg * 16 + cgrp];

    if (chunk + K3_THREADS * K3_ITERS <= total4) {
        #pragma unroll
        for (int k = 0; k < K3_ITERS; ++k) {
            long i = chunk + (long)k * K3_THREADS + tid;
            f32x4 v = x4[i];
            f32x4 o;
            o.x = v.x * sc.x + sh.x;
            o.y = v.y * sc.y + sh.y;
            o.z = v.z * sc.z + sh.z;
            o.w = v.w * sc.w + sh.w;
            __builtin_nontemporal_store(o, &y4[i]);
        }
    } else {
        for (int k = 0; k < K3_ITERS; ++k) {
            long i = chunk + (long)k * K3_THREADS + tid;
            if (i < total4) {
                f32x4 v = x4[i];
                f32x4 o;
                o.x = v.x * sc.x + sh.x;
                o.y = v.y * sc.y + sh.y;
                o.z = v.z * sc.z + sh.z;
                o.w = v.w * sc.w + sh.w;
                __builtin_nontemporal_store(o, &y4[i]);
            }
        }
    }
}

// ---------------------------------------------------------------- launcher
extern "C" void kernel_launch(void* const* d_in, const int* in_sizes, int n_in,
                              void* d_out, int out_size, void* d_ws, size_t ws_size,
                              hipStream_t stream) {
    const float* x       = (const float*)d_in[0];
    const float* weight  = (const float*)d_in[1];
    const float* bias    = (const float*)d_in[2];
    const int*   offs    = (const int*)d_in[3];
    const int*   bidx    = (const int*)d_in[4];
    float* out = (float*)d_out;

    const long C = in_sizes[1];          // 64
    const long N = (long)in_sizes[0] / C;
    const int  S = in_sizes[3] - 1;      // number of segments

    // ppb=1024 (proven; 1024 chunks @ N=1M)
    int ppb = 1024;
    long nb1;
    for (;;) {
        nb1 = (N + ppb - 1) / ppb;
        size_t need = (size_t)(nb1 * 128 + 2 * S * 64) * sizeof(float);
        if (need <= ws_size || ppb >= (1 << 20)) break;
        ppb <<= 1;
    }

    float* partials = (float*)d_ws;
    float* scale    = partials + nb1 * 128;
    float* shift    = scale + S * 64;

    pin_stats<<<(int)nb1, 256, 0, stream>>>((const float4*)x, partials, ppb, N);
    pin_scale<<<S, 256, 0, stream>>>(partials, weight, bias, offs, scale, shift, ppb);

    const long total4 = N * (C / 4);
    const long nb3 = (total4 + (K3_THREADS * K3_ITERS) - 1) / (K3_THREADS * K3_ITERS);
    pin_norm<<<(int)nb3, K3_THREADS, 0, stream>>>(
        (const f32x4*)x, bidx, (const float4*)scale, (const float4*)shift,
        (f32x4*)out, total4);
}